// Round 13
// baseline (468.981 us; speedup 1.0000x reference)
//
#include <hip/hip_runtime.h>
#include <math.h>

#define N_TOK 131072
#define DIM   64
#define QS    8
#define KS    1024

typedef _Float16 f16x8 __attribute__((ext_vector_type(8)));
typedef float    f32x4 __attribute__((ext_vector_type(4)));

#define RSCALE   2048.0f
#define RISCALE  4.8828125e-4f   // 2^-11

// split fp32 v into f16 limbs + scaled-hi: v ~= hi + lo*2^-11 ; hs = 2048*hi (exact)
#define SPLIT3(v, hi, lo, hs) { _Float16 _h = (_Float16)(v); (hi) = _h;        \
                                (lo) = (_Float16)(((v) - (float)_h) * RSCALE); \
                                (hs) = (_Float16)((float)_h * RSCALE); }

// ---- workspace layout G: 128 chunks, each 16640 B:
//   [0    .. 16383]  frag limbs: 16 sub-slots of 1KB (4 groups x {h0,h1,l0,l1})
//   [16384.. 16639]  64 floats: -1024*||c||^2 seeds for the chunk's 64 codewords
// Chunk c covers stage q = c>>4, codewords (c&15)*64 .. +63.

// ---- pre-pass 1: codebook -> f16 limbs in MFMA fragment order.
// slot = (q*64+g)*4 + l*2 + h ; chunk c = slot>>4, sub = slot&15.
__global__ void conv_kernel(const float* __restrict__ cb, _Float16* __restrict__ G) {
    int t = blockIdx.x * blockDim.x + threadIdx.x;
    if (t >= 2048 * 64) return;
    const int lane = t & 63, slot = t >> 6;
    const int h = slot & 1, l = (slot >> 1) & 1, g = (slot >> 2) & 63, q = slot >> 8;
    const int cw = g * 16 + (lane & 15);
    const int d0 = h * 32 + (lane >> 4) * 8;
    const float* src = cb + ((size_t)q * KS + cw) * DIM + d0;
    f16x8 v;
#pragma unroll
    for (int j = 0; j < 8; ++j) {
        float c = src[j];
        _Float16 hi = (_Float16)c;
        v[j] = (l == 0) ? hi : (_Float16)((c - (float)hi) * RSCALE);
    }
    const int c = slot >> 4, w = slot & 15;
    *(f16x8*)(G + (size_t)c * 8320 + w * 512 + lane * 8) = v;
}

// ---- pre-pass 2: dc2 seeds written straight into each chunk's tail ----
__global__ void dc2_kernel(const float* __restrict__ cb, float* __restrict__ Gf) {
    int i = blockIdx.x * blockDim.x + threadIdx.x;
    if (i < QS * KS) {
        const float* c = cb + (size_t)i * DIM;
        float s = 0.f;
#pragma unroll
        for (int d = 0; d < DIM; ++d) s = fmaf(c[d], c[d], s);
        const int q = i >> 10, k = i & 1023;
        const int ch = q * 16 + (k >> 6), j = k & 63;
        Gf[(size_t)ch * 4160 + 4096 + j] = -1024.0f * s;
    }
}

#define CHUNK_B   16640     // bytes per chunk (16KB frags + 256B dc2)
#define CHUNK_H   8320      // _Float16 elements per chunk
#define DC2_OFF_H 8192      // half-offset of dc2 region (byte 16384)

// ---- main: r8 structure (4 token-sets/wave, pair-intervals, setprio; 381us)
// with the COMPUTE restructured into 12 INDEPENDENT depth-2 MFMA chains
// (3 limb-products x 4 sets, seeded {CIV,0,0}, summed before argmin).
// Rationale: r8/r12 sit at MfmaUtil+VALUBusy ~ 96% with per-wave MFMA duty
// ~26%; the depth-6 chains' critical path (6 x ~116cyc dep latency = ~700)
// exceeds the 24-MFMA issue window (~465cyc) -> ~940 cyc bubble per chunk.
// Depth-2 chains cut the critical path to ~232 < 465.
__global__ __launch_bounds__(256, 2)
void rvq_mfma_kernel(const float* __restrict__ x,
                     const float* __restrict__ cbf,
                     const _Float16* __restrict__ F,
                     float* __restrict__ out) {
    extern __shared__ _Float16 smem[];   // 2 buffers x 2 chunks x CHUNK_H = 66560 B

    const int tid  = threadIdx.x;
    const int wave = tid >> 6;
    const int lane = tid & 63;
    const int quad = lane >> 4;
    const int m    = lane & 15;
    const int quad4 = quad * 4;

    const int tokenBase = blockIdx.x * 256 + wave * 64;

    // token limbs, 4 sets (B-frag layout): th = hi, tl = 2048*(r-hi), ts = 2048*hi
    f16x8 th00, th01, tl00, tl01, ts00, ts01;
    f16x8 th10, th11, tl10, tl11, ts10, ts11;
    f16x8 th20, th21, tl20, tl21, ts20, ts21;
    f16x8 th30, th31, tl30, tl31, ts30, ts31;

#define LOADTOK(S, TH0, TH1, TL0, TL1, TS0, TS1) {                                \
        const float* xa = x + (size_t)(tokenBase + (S) * 16 + m) * DIM + quad * 8;\
        f32x4 a0 = __builtin_nontemporal_load((const f32x4*)(xa));                \
        f32x4 a1 = __builtin_nontemporal_load((const f32x4*)(xa + 4));            \
        f32x4 a2 = __builtin_nontemporal_load((const f32x4*)(xa + 32));           \
        f32x4 a3 = __builtin_nontemporal_load((const f32x4*)(xa + 36));           \
        _Pragma("unroll")                                                         \
        for (int j = 0; j < 4; ++j) {                                             \
            SPLIT3(a0[j], TH0[j],   TL0[j],   TS0[j]);                            \
            SPLIT3(a1[j], TH0[j+4], TL0[j+4], TS0[j+4]);                          \
            SPLIT3(a2[j], TH1[j],   TL1[j],   TS1[j]);                            \
            SPLIT3(a3[j], TH1[j+4], TL1[j+4], TS1[j+4]);                          \
        }                                                                         \
    }
    LOADTOK(0, th00, th01, tl00, tl01, ts00, ts01);
    LOADTOK(1, th10, th11, tl10, tl11, ts10, ts11);
    LOADTOK(2, th20, th21, tl20, tl21, ts20, ts21);
    LOADTOK(3, th30, th31, tl30, tl31, ts30, ts31);

// stage chunk GC into pair-buffer BUF, slot J (0/1).
#define STAGE(GC, BUF, J) {                                                       \
        const char* _gs = (const char*)F + (size_t)(GC) * CHUNK_B                 \
                          + (wave << 10) + (lane << 4);                           \
        _Float16* _ld = smem + (BUF) * (2 * CHUNK_H) + (J) * CHUNK_H              \
                        + (wave << 9);                                            \
        _Pragma("unroll")                                                         \
        for (int _j = 0; _j < 4; ++_j)                                            \
            __builtin_amdgcn_global_load_lds(                                     \
                (const __attribute__((address_space(1))) void*)(_gs + _j * 4096), \
                (__attribute__((address_space(3))) void*)(_ld + _j * 2048),       \
                16, 0, 0);                                                        \
        if (wave == 0) {                                                          \
            const char* _gd = (const char*)F + (size_t)(GC) * CHUNK_B + 16384     \
                              + (lane << 2);                                      \
            __builtin_amdgcn_global_load_lds(                                     \
                (const __attribute__((address_space(1))) void*)_gd,               \
                (__attribute__((address_space(3))) void*)(smem                    \
                    + (BUF) * (2 * CHUNK_H) + (J) * CHUNK_H + DC2_OFF_H),         \
                4, 0, 0);                                                         \
        }                                                                         \
    }

// One group: 24 MFMAs as 12 INDEPENDENT depth-2 chains (3 limb-products x
// 4 sets), seeded {CIV, 0, 0}; summed with packed adds before argmin.
// Same FLOPs/traffic as depth-6; critical path 2 deps instead of 6.
#define COMPUTE(CH0, CH1, CL0, CL1, CIV, G) {                                       \
        f32x4 _z = {0.f, 0.f, 0.f, 0.f};                                            \
        __builtin_amdgcn_s_setprio(1);                                              \
        f32x4 S0 = __builtin_amdgcn_mfma_f32_16x16x32_f16(CH0, ts00, CIV, 0,0,0);   \
        f32x4 S1 = __builtin_amdgcn_mfma_f32_16x16x32_f16(CH0, ts10, CIV, 0,0,0);   \
        f32x4 S2 = __builtin_amdgcn_mfma_f32_16x16x32_f16(CH0, ts20, CIV, 0,0,0);   \
        f32x4 S3 = __builtin_amdgcn_mfma_f32_16x16x32_f16(CH0, ts30, CIV, 0,0,0);   \
        f32x4 H0 = __builtin_amdgcn_mfma_f32_16x16x32_f16(CL0, th00, _z, 0,0,0);    \
        f32x4 H1 = __builtin_amdgcn_mfma_f32_16x16x32_f16(CL0, th10, _z, 0,0,0);    \
        f32x4 H2 = __builtin_amdgcn_mfma_f32_16x16x32_f16(CL0, th20, _z, 0,0,0);    \
        f32x4 H3 = __builtin_amdgcn_mfma_f32_16x16x32_f16(CL0, th30, _z, 0,0,0);    \
        f32x4 L0 = __builtin_amdgcn_mfma_f32_16x16x32_f16(CH0, tl00, _z, 0,0,0);    \
        f32x4 L1 = __builtin_amdgcn_mfma_f32_16x16x32_f16(CH0, tl10, _z, 0,0,0);    \
        f32x4 L2 = __builtin_amdgcn_mfma_f32_16x16x32_f16(CH0, tl20, _z, 0,0,0);    \
        f32x4 L3 = __builtin_amdgcn_mfma_f32_16x16x32_f16(CH0, tl30, _z, 0,0,0);    \
        S0 = __builtin_amdgcn_mfma_f32_16x16x32_f16(CH1, ts01, S0, 0,0,0);          \
        S1 = __builtin_amdgcn_mfma_f32_16x16x32_f16(CH1, ts11, S1, 0,0,0);          \
        S2 = __builtin_amdgcn_mfma_f32_16x16x32_f16(CH1, ts21, S2, 0,0,0);          \
        S3 = __builtin_amdgcn_mfma_f32_16x16x32_f16(CH1, ts31, S3, 0,0,0);          \
        H0 = __builtin_amdgcn_mfma_f32_16x16x32_f16(CL1, th01, H0, 0,0,0);          \
        H1 = __builtin_amdgcn_mfma_f32_16x16x32_f16(CL1, th11, H1, 0,0,0);          \
        H2 = __builtin_amdgcn_mfma_f32_16x16x32_f16(CL1, th21, H2, 0,0,0);          \
        H3 = __builtin_amdgcn_mfma_f32_16x16x32_f16(CL1, th31, H3, 0,0,0);          \
        L0 = __builtin_amdgcn_mfma_f32_16x16x32_f16(CH1, tl01, L0, 0,0,0);          \
        L1 = __builtin_amdgcn_mfma_f32_16x16x32_f16(CH1, tl11, L1, 0,0,0);          \
        L2 = __builtin_amdgcn_mfma_f32_16x16x32_f16(CH1, tl21, L2, 0,0,0);          \
        L3 = __builtin_amdgcn_mfma_f32_16x16x32_f16(CH1, tl31, L3, 0,0,0);          \
        __builtin_amdgcn_s_setprio(0);                                              \
        f32x4 A0 = (S0 + H0) + L0;                                                  \
        f32x4 A1 = (S1 + H1) + L1;                                                  \
        f32x4 A2 = (S2 + H2) + L2;                                                  \
        f32x4 A3 = (S3 + H3) + L3;                                                  \
        const int base = (G) * 16 + quad4;                                          \
        _Pragma("unroll")                                                           \
        for (int i = 0; i < 4; ++i) {                                               \
            if (A0[i] > bv0) { bv0 = A0[i]; bi0 = base + i; }                       \
            if (A1[i] > bv1) { bv1 = A1[i]; bi1 = base + i; }                       \
            if (A2[i] > bv2) { bv2 = A2[i]; bi2 = base + i; }                       \
            if (A3[i] > bv3) { bv3 = A3[i]; bi3 = base + i; }                       \
        }                                                                           \
    }

// one chunk's compute (4 groups), register double-buffer over groups
#define CHUNKBODY(LBASE, GBASE) {                                                 \
        const _Float16* L   = (LBASE) + lane * 8;                                 \
        const float*    dcL = (const float*)((LBASE) + DC2_OFF_H);                \
        f32x4 ci0 = *(const f32x4*)(dcL +  0 + quad4);                            \
        f32x4 ci1 = *(const f32x4*)(dcL + 16 + quad4);                            \
        f32x4 ci2 = *(const f32x4*)(dcL + 32 + quad4);                            \
        f32x4 ci3 = *(const f32x4*)(dcL + 48 + quad4);                            \
        f16x8 g0h0 = *(const f16x8*)(L);                                          \
        f16x8 g0h1 = *(const f16x8*)(L + 512);                                    \
        f16x8 g0l0 = *(const f16x8*)(L + 1024);                                   \
        f16x8 g0l1 = *(const f16x8*)(L + 1536);                                   \
        f16x8 g1h0 = *(const f16x8*)(L + 2048);                                   \
        f16x8 g1h1 = *(const f16x8*)(L + 2560);                                   \
        f16x8 g1l0 = *(const f16x8*)(L + 3072);                                   \
        f16x8 g1l1 = *(const f16x8*)(L + 3584);                                   \
        COMPUTE(g0h0, g0h1, g0l0, g0l1, ci0, (GBASE) + 0);                        \
        g0h0 = *(const f16x8*)(L + 4096);                                         \
        g0h1 = *(const f16x8*)(L + 4608);                                         \
        g0l0 = *(const f16x8*)(L + 5120);                                         \
        g0l1 = *(const f16x8*)(L + 5632);                                         \
        COMPUTE(g1h0, g1h1, g1l0, g1l1, ci1, (GBASE) + 1);                        \
        g1h0 = *(const f16x8*)(L + 6144);                                         \
        g1h1 = *(const f16x8*)(L + 6656);                                         \
        g1l0 = *(const f16x8*)(L + 7168);                                         \
        g1l1 = *(const f16x8*)(L + 7680);                                         \
        COMPUTE(g0h0, g0h1, g0l0, g0l1, ci2, (GBASE) + 2);                        \
        COMPUTE(g1h0, g1h1, g1l0, g1l1, ci3, (GBASE) + 3);                        \
    }

    // prologue: stage pair 0 (chunks 0,1) into buffer 0
    STAGE(0, 0, 0);
    STAGE(1, 0, 1);
    __syncthreads();
    int cur = 0;

    for (int q = 0; q < QS; ++q) {
        const float* cfq = cbf + (size_t)q * KS * DIM;

        float bv0 = -INFINITY, bv1 = -INFINITY, bv2 = -INFINITY, bv3 = -INFINITY;
        int   bi0 = 0, bi1 = 0, bi2 = 0, bi3 = 0;

        for (int p = 0; p < 8; ++p) {
            const int gp = (q << 3) | p;            // global pair 0..63
            if (gp + 1 < 64) {                      // prefetch next pair
                STAGE(2 * gp + 2, cur ^ 1, 0);
                STAGE(2 * gp + 3, cur ^ 1, 1);
            }

            _Float16* base = smem + cur * (2 * CHUNK_H);
            CHUNKBODY(base,           (p * 2 + 0) * 4);
            CHUNKBODY(base + CHUNK_H, (p * 2 + 1) * 4);

            // barrier (with implicit vmcnt/lgkm drain): staged pair gp+1
            // resident; all waves done reading buffer cur.
            __syncthreads();
            cur ^= 1;
        }

        // reduce over the 4 quad-lanes holding the same token (disjoint codewords):
        // 2 shuffle steps. Tie-break: lowest index, matching jnp.argmin.
#define REDUCE(BV, BI) {                                                          \
        _Pragma("unroll")                                                         \
        for (int mask = 16; mask <= 32; mask <<= 1) {                             \
            float ov = __shfl_xor(BV, mask, 64);                                  \
            int   oi = __shfl_xor(BI, mask, 64);                                  \
            if (ov > BV || (ov == BV && oi < BI)) { BV = ov; BI = oi; }           \
        }                                                                         \
    }
        REDUCE(bv0, bi0); REDUCE(bv1, bi1); REDUCE(bv2, bi2); REDUCE(bv3, bi3);

        // index writes: quad s writes set s's token (64 lanes = 64 tokens)
        {
            const int myTok = tokenBase + quad * 16 + m;
            const int mybi  = (quad == 0) ? bi0 : (quad == 1) ? bi1
                            : (quad == 2) ? bi2 : bi3;
            out[(size_t)N_TOK * DIM + (size_t)myTok * QS + q] = (float)mybi;
        }

        // residual update per set: reconstruct r, subtract fp32 codeword, re-split
        float ls = 0.f;
#define RESID(BI, TH0, TH1, TL0, TL1, TS0, TS1) {                                 \
        const float* cp = cfq + (size_t)(BI) * DIM + quad * 8;                    \
        f32x4 c0 = *(const f32x4*)(cp);                                           \
        f32x4 c1 = *(const f32x4*)(cp + 4);                                       \
        f32x4 c2 = *(const f32x4*)(cp + 32);                                      \
        f32x4 c3 = *(const f32x4*)(cp + 36);                                      \
        _Pragma("unroll")                                                         \
        for (int j = 0; j < 4; ++j) {                                             \
            float v0 = fmaf(RISCALE, (float)TL0[j],   (float)TH0[j])   - c0[j];   \
            float v1 = fmaf(RISCALE, (float)TL0[j+4], (float)TH0[j+4]) - c1[j];   \
            float v2 = fmaf(RISCALE, (float)TL1[j],   (float)TH1[j])   - c2[j];   \
            float v3 = fmaf(RISCALE, (float)TL1[j+4], (float)TH1[j+4]) - c3[j];   \
            ls = fmaf(v0, v0, ls); ls = fmaf(v1, v1, ls);                         \
            ls = fmaf(v2, v2, ls); ls = fmaf(v3, v3, ls);                         \
            SPLIT3(v0, TH0[j],   TL0[j],   TS0[j]);                               \
            SPLIT3(v1, TH0[j+4], TL0[j+4], TS0[j+4]);                             \
            SPLIT3(v2, TH1[j],   TL1[j],   TS1[j]);                               \
            SPLIT3(v3, TH1[j+4], TL1[j+4], TS1[j+4]);                             \
        }                                                                         \
    }
        RESID(bi0, th00, th01, tl00, tl01, ts00, ts01);
        RESID(bi1, th10, th11, tl10, tl11, ts10, ts11);
        RESID(bi2, th20, th21, tl20, tl21, ts20, ts21);
        RESID(bi3, th30, th31, tl30, tl31, ts30, ts31);

#pragma unroll
        for (int mask = 1; mask <= 32; mask <<= 1) ls += __shfl_xor(ls, mask, 64);
        if (lane == 0)
            atomicAdd(out + (size_t)N_TOK * DIM + (size_t)N_TOK * QS + q,
                      ls * (1.0f / ((float)N_TOK * (float)DIM)));
    }

    // xq = x - r_final (reconstruct final residual from limbs), per set
#define XQW(S, TH0, TH1, TL0, TL1) {                                              \
        const size_t ra = (size_t)(tokenBase + (S) * 16 + m) * DIM + quad * 8;    \
        f32x4 a0 = __builtin_nontemporal_load((const f32x4*)(x + ra));            \
        f32x4 a1 = __builtin_nontemporal_load((const f32x4*)(x + ra + 4));        \
        f32x4 a2 = __builtin_nontemporal_load((const f32x4*)(x + ra + 32));       \
        f32x4 a3 = __builtin_nontemporal_load((const f32x4*)(x + ra + 36));       \
        _Pragma("unroll")                                                         \
        for (int j = 0; j < 4; ++j) {                                             \
            a0[j] -= fmaf(RISCALE, (float)TL0[j],   (float)TH0[j]);               \
            a1[j] -= fmaf(RISCALE, (float)TL0[j+4], (float)TH0[j+4]);             \
            a2[j] -= fmaf(RISCALE, (float)TL1[j],   (float)TH1[j]);               \
            a3[j] -= fmaf(RISCALE, (float)TL1[j+4], (float)TH1[j+4]);             \
        }                                                                         \
        __builtin_nontemporal_store(a0, (f32x4*)(out + ra));                      \
        __builtin_nontemporal_store(a1, (f32x4*)(out + ra + 4));                  \
        __builtin_nontemporal_store(a2, (f32x4*)(out + ra + 32));                 \
        __builtin_nontemporal_store(a3, (f32x4*)(out + ra + 36));                 \
    }
    XQW(0, th00, th01, tl00, tl01);
    XQW(1, th10, th11, tl10, tl11);
    XQW(2, th20, th21, tl20, tl21);
    XQW(3, th30, th31, tl30, tl31);

#undef COMPUTE
#undef CHUNKBODY
#undef STAGE
#undef LOADTOK
#undef REDUCE
#undef RESID
#undef XQW
}

extern "C" void kernel_launch(void* const* d_in, const int* in_sizes, int n_in,
                              void* d_out, int out_size, void* d_ws, size_t ws_size,
                              hipStream_t stream) {
    const float* x   = (const float*)d_in[0];   // (N, D)
    const float* cb  = (const float*)d_in[1];   // (Q, K, D)
    float*       out = (float*)d_out;           // [xq | indices | losses]
    char*        ws  = (char*)d_ws;

    _Float16* G = (_Float16*)ws;   // 128 chunks x 16640 B = 2,129,920 B

    hipMemsetAsync(out + (size_t)N_TOK * DIM + (size_t)N_TOK * QS, 0,
                   QS * sizeof(float), stream);

    conv_kernel<<<512, 256, 0, stream>>>(cb, G);
    dc2_kernel<<<(QS * KS + 255) / 256, 256, 0, stream>>>(cb, (float*)ws);
    rvq_mfma_kernel<<<N_TOK / 256, 256, 4 * CHUNK_H * sizeof(_Float16), stream>>>(
        x, cb, G, out);
}

// Round 14
// 425.594 us; speedup vs baseline: 1.1019x; 1.1019x over previous
//
#include <hip/hip_runtime.h>
#include <math.h>

#define N_TOK 131072
#define DIM   64
#define QS    8
#define KS    1024

typedef _Float16 f16x8 __attribute__((ext_vector_type(8)));
typedef float    f32x4 __attribute__((ext_vector_type(4)));

#define RSCALE   2048.0f
#define RISCALE  4.8828125e-4f   // 2^-11

// split fp32 v into f16 limbs + scaled-hi: v ~= hi + lo*2^-11 ; hs = 2048*hi (exact)
#define SPLIT3(v, hi, lo, hs) { _Float16 _h = (_Float16)(v); (hi) = _h;        \
                                (lo) = (_Float16)(((v) - (float)_h) * RSCALE); \
                                (hs) = (_Float16)((float)_h * RSCALE); }

// ---- workspace layout G: 128 chunks, each 16640 B:
//   [0    .. 16383]  frag limbs: 16 sub-slots of 1KB (4 groups x {h0,h1,l0,l1})
//   [16384.. 16639]  64 floats: -1024*||c||^2 seeds for the chunk's 64 codewords
// Chunk c covers stage q = c>>4, codewords (c&15)*64 .. +63.

// ---- pre-pass 1: codebook -> f16 limbs in MFMA fragment order.
// slot = (q*64+g)*4 + l*2 + h ; chunk c = slot>>4, sub = slot&15.
__global__ void conv_kernel(const float* __restrict__ cb, _Float16* __restrict__ G) {
    int t = blockIdx.x * blockDim.x + threadIdx.x;
    if (t >= 2048 * 64) return;
    const int lane = t & 63, slot = t >> 6;
    const int h = slot & 1, l = (slot >> 1) & 1, g = (slot >> 2) & 63, q = slot >> 8;
    const int cw = g * 16 + (lane & 15);
    const int d0 = h * 32 + (lane >> 4) * 8;
    const float* src = cb + ((size_t)q * KS + cw) * DIM + d0;
    f16x8 v;
#pragma unroll
    for (int j = 0; j < 8; ++j) {
        float c = src[j];
        _Float16 hi = (_Float16)c;
        v[j] = (l == 0) ? hi : (_Float16)((c - (float)hi) * RSCALE);
    }
    const int c = slot >> 4, w = slot & 15;
    *(f16x8*)(G + (size_t)c * 8320 + w * 512 + lane * 8) = v;
}

// ---- pre-pass 2: dc2 seeds written straight into each chunk's tail ----
__global__ void dc2_kernel(const float* __restrict__ cb, float* __restrict__ Gf) {
    int i = blockIdx.x * blockDim.x + threadIdx.x;
    if (i < QS * KS) {
        const float* c = cb + (size_t)i * DIM;
        float s = 0.f;
#pragma unroll
        for (int d = 0; d < DIM; ++d) s = fmaf(c[d], c[d], s);
        const int q = i >> 10, k = i & 1023;
        const int ch = q * 16 + (k >> 6), j = k & 63;
        Gf[(size_t)ch * 4160 + 4096 + j] = -1024.0f * s;
    }
}

#define CHUNK_B   16640     // bytes per chunk (16KB frags + 256B dc2)
#define CHUNK_H   8320      // _Float16 elements per chunk
#define DC2_OFF_H 8192      // half-offset of dc2 region (byte 16384)

// ---- main: r8 structure (4 token-sets/wave, pair-intervals; 381us best) with
// (a) setprio REMOVED (it acts as a scheduling fence around each 24-MFMA
// cluster; T5's prereq -- phase-split waves -- doesn't hold in this lockstep
// structure, m190 measured it negative there), and (b) argmin DEFERRED one
// group: issue group g+1's 24 MFMAs, THEN run group g's argmin, so the
// compare VALU fills g+1's pipe-latency window instead of stalling on g's
// last MFMA result. Comparison order (groups ascending, elements ascending)
// unchanged -> numerics and tie-break bit-identical to r8.
__global__ __launch_bounds__(256, 2)
void rvq_mfma_kernel(const float* __restrict__ x,
                     const float* __restrict__ cbf,
                     const _Float16* __restrict__ F,
                     float* __restrict__ out) {
    extern __shared__ _Float16 smem[];   // 2 buffers x 2 chunks x CHUNK_H = 66560 B

    const int tid  = threadIdx.x;
    const int wave = tid >> 6;
    const int lane = tid & 63;
    const int quad = lane >> 4;
    const int m    = lane & 15;
    const int quad4 = quad * 4;

    const int tokenBase = blockIdx.x * 256 + wave * 64;

    // token limbs, 4 sets (B-frag layout): th = hi, tl = 2048*(r-hi), ts = 2048*hi
    f16x8 th00, th01, tl00, tl01, ts00, ts01;
    f16x8 th10, th11, tl10, tl11, ts10, ts11;
    f16x8 th20, th21, tl20, tl21, ts20, ts21;
    f16x8 th30, th31, tl30, tl31, ts30, ts31;

#define LOADTOK(S, TH0, TH1, TL0, TL1, TS0, TS1) {                                \
        const float* xa = x + (size_t)(tokenBase + (S) * 16 + m) * DIM + quad * 8;\
        f32x4 a0 = __builtin_nontemporal_load((const f32x4*)(xa));                \
        f32x4 a1 = __builtin_nontemporal_load((const f32x4*)(xa + 4));            \
        f32x4 a2 = __builtin_nontemporal_load((const f32x4*)(xa + 32));           \
        f32x4 a3 = __builtin_nontemporal_load((const f32x4*)(xa + 36));           \
        _Pragma("unroll")                                                         \
        for (int j = 0; j < 4; ++j) {                                             \
            SPLIT3(a0[j], TH0[j],   TL0[j],   TS0[j]);                            \
            SPLIT3(a1[j], TH0[j+4], TL0[j+4], TS0[j+4]);                          \
            SPLIT3(a2[j], TH1[j],   TL1[j],   TS1[j]);                            \
            SPLIT3(a3[j], TH1[j+4], TL1[j+4], TS1[j+4]);                          \
        }                                                                         \
    }
    LOADTOK(0, th00, th01, tl00, tl01, ts00, ts01);
    LOADTOK(1, th10, th11, tl10, tl11, ts10, ts11);
    LOADTOK(2, th20, th21, tl20, tl21, ts20, ts21);
    LOADTOK(3, th30, th31, tl30, tl31, ts30, ts31);

// stage chunk GC into pair-buffer BUF, slot J (0/1).
#define STAGE(GC, BUF, J) {                                                       \
        const char* _gs = (const char*)F + (size_t)(GC) * CHUNK_B                 \
                          + (wave << 10) + (lane << 4);                           \
        _Float16* _ld = smem + (BUF) * (2 * CHUNK_H) + (J) * CHUNK_H              \
                        + (wave << 9);                                            \
        _Pragma("unroll")                                                         \
        for (int _j = 0; _j < 4; ++_j)                                            \
            __builtin_amdgcn_global_load_lds(                                     \
                (const __attribute__((address_space(1))) void*)(_gs + _j * 4096), \
                (__attribute__((address_space(3))) void*)(_ld + _j * 2048),       \
                16, 0, 0);                                                        \
        if (wave == 0) {                                                          \
            const char* _gd = (const char*)F + (size_t)(GC) * CHUNK_B + 16384     \
                              + (lane << 2);                                      \
            __builtin_amdgcn_global_load_lds(                                     \
                (const __attribute__((address_space(1))) void*)_gd,               \
                (__attribute__((address_space(3))) void*)(smem                    \
                    + (BUF) * (2 * CHUNK_H) + (J) * CHUNK_H + DC2_OFF_H),         \
                4, 0, 0);                                                         \
        }                                                                         \
    }

// 24 MFMAs: 4 independent depth-6 chains (one per token-set), shared A-frags.
// Pure MFMA cluster -- no fences, no argmin; accs written to A0..A3.
#define MFMA24(CH0, CH1, CL0, CL1, CIV, A0, A1, A2, A3) {                           \
        A0 = __builtin_amdgcn_mfma_f32_16x16x32_f16(CH0, ts00, CIV, 0,0,0);         \
        A1 = __builtin_amdgcn_mfma_f32_16x16x32_f16(CH0, ts10, CIV, 0,0,0);         \
        A2 = __builtin_amdgcn_mfma_f32_16x16x32_f16(CH0, ts20, CIV, 0,0,0);         \
        A3 = __builtin_amdgcn_mfma_f32_16x16x32_f16(CH0, ts30, CIV, 0,0,0);         \
        A0 = __builtin_amdgcn_mfma_f32_16x16x32_f16(CH1, ts01, A0, 0,0,0);          \
        A1 = __builtin_amdgcn_mfma_f32_16x16x32_f16(CH1, ts11, A1, 0,0,0);          \
        A2 = __builtin_amdgcn_mfma_f32_16x16x32_f16(CH1, ts21, A2, 0,0,0);          \
        A3 = __builtin_amdgcn_mfma_f32_16x16x32_f16(CH1, ts31, A3, 0,0,0);          \
        A0 = __builtin_amdgcn_mfma_f32_16x16x32_f16(CL0, th00, A0, 0,0,0);          \
        A1 = __builtin_amdgcn_mfma_f32_16x16x32_f16(CL0, th10, A1, 0,0,0);          \
        A2 = __builtin_amdgcn_mfma_f32_16x16x32_f16(CL0, th20, A2, 0,0,0);          \
        A3 = __builtin_amdgcn_mfma_f32_16x16x32_f16(CL0, th30, A3, 0,0,0);          \
        A0 = __builtin_amdgcn_mfma_f32_16x16x32_f16(CL1, th01, A0, 0,0,0);          \
        A1 = __builtin_amdgcn_mfma_f32_16x16x32_f16(CL1, th11, A1, 0,0,0);          \
        A2 = __builtin_amdgcn_mfma_f32_16x16x32_f16(CL1, th21, A2, 0,0,0);          \
        A3 = __builtin_amdgcn_mfma_f32_16x16x32_f16(CL1, th31, A3, 0,0,0);          \
        A0 = __builtin_amdgcn_mfma_f32_16x16x32_f16(CH0, tl00, A0, 0,0,0);          \
        A1 = __builtin_amdgcn_mfma_f32_16x16x32_f16(CH0, tl10, A1, 0,0,0);          \
        A2 = __builtin_amdgcn_mfma_f32_16x16x32_f16(CH0, tl20, A2, 0,0,0);          \
        A3 = __builtin_amdgcn_mfma_f32_16x16x32_f16(CH0, tl30, A3, 0,0,0);          \
        A0 = __builtin_amdgcn_mfma_f32_16x16x32_f16(CH1, tl01, A0, 0,0,0);          \
        A1 = __builtin_amdgcn_mfma_f32_16x16x32_f16(CH1, tl11, A1, 0,0,0);          \
        A2 = __builtin_amdgcn_mfma_f32_16x16x32_f16(CH1, tl21, A2, 0,0,0);          \
        A3 = __builtin_amdgcn_mfma_f32_16x16x32_f16(CH1, tl31, A3, 0,0,0);          \
    }

// argmin scan of one group's accs (4 sets x 4 elems, ascending -> tie-break ok)
#define ARGMIN(A0, A1, A2, A3, G) {                                                \
        const int base = (G) * 16 + quad4;                                         \
        _Pragma("unroll")                                                          \
        for (int i = 0; i < 4; ++i) {                                              \
            if (A0[i] > bv0) { bv0 = A0[i]; bi0 = base + i; }                      \
            if (A1[i] > bv1) { bv1 = A1[i]; bi1 = base + i; }                      \
            if (A2[i] > bv2) { bv2 = A2[i]; bi2 = base + i; }                      \
            if (A3[i] > bv3) { bv3 = A3[i]; bi3 = base + i; }                      \
        }                                                                          \
    }

// one chunk's compute: 4 groups, register double-buffer over frags, argmin
// pipelined one group deep (group g's argmin after group g+1's MFMAs issue).
#define CHUNKBODY(LBASE, GBASE) {                                                 \
        const _Float16* L   = (LBASE) + lane * 8;                                 \
        const float*    dcL = (const float*)((LBASE) + DC2_OFF_H);                \
        f32x4 ci0 = *(const f32x4*)(dcL +  0 + quad4);                            \
        f32x4 ci1 = *(const f32x4*)(dcL + 16 + quad4);                            \
        f32x4 ci2 = *(const f32x4*)(dcL + 32 + quad4);                            \
        f32x4 ci3 = *(const f32x4*)(dcL + 48 + quad4);                            \
        f16x8 g0h0 = *(const f16x8*)(L);                                          \
        f16x8 g0h1 = *(const f16x8*)(L + 512);                                    \
        f16x8 g0l0 = *(const f16x8*)(L + 1024);                                   \
        f16x8 g0l1 = *(const f16x8*)(L + 1536);                                   \
        f16x8 g1h0 = *(const f16x8*)(L + 2048);                                   \
        f16x8 g1h1 = *(const f16x8*)(L + 2560);                                   \
        f16x8 g1l0 = *(const f16x8*)(L + 3072);                                   \
        f16x8 g1l1 = *(const f16x8*)(L + 3584);                                   \
        f32x4 pA0, pA1, pA2, pA3, pB0, pB1, pB2, pB3;                             \
        MFMA24(g0h0, g0h1, g0l0, g0l1, ci0, pA0, pA1, pA2, pA3);                  \
        g0h0 = *(const f16x8*)(L + 4096);                                         \
        g0h1 = *(const f16x8*)(L + 4608);                                         \
        g0l0 = *(const f16x8*)(L + 5120);                                         \
        g0l1 = *(const f16x8*)(L + 5632);                                         \
        MFMA24(g1h0, g1h1, g1l0, g1l1, ci1, pB0, pB1, pB2, pB3);                  \
        ARGMIN(pA0, pA1, pA2, pA3, (GBASE) + 0);                                  \
        g1h0 = *(const f16x8*)(L + 6144);                                         \
        g1h1 = *(const f16x8*)(L + 6656);                                         \
        g1l0 = *(const f16x8*)(L + 7168);                                         \
        g1l1 = *(const f16x8*)(L + 7680);                                         \
        MFMA24(g0h0, g0h1, g0l0, g0l1, ci2, pA0, pA1, pA2, pA3);                  \
        ARGMIN(pB0, pB1, pB2, pB3, (GBASE) + 1);                                  \
        MFMA24(g1h0, g1h1, g1l0, g1l1, ci3, pB0, pB1, pB2, pB3);                  \
        ARGMIN(pA0, pA1, pA2, pA3, (GBASE) + 2);                                  \
        ARGMIN(pB0, pB1, pB2, pB3, (GBASE) + 3);                                  \
    }

    // prologue: stage pair 0 (chunks 0,1) into buffer 0
    STAGE(0, 0, 0);
    STAGE(1, 0, 1);
    __syncthreads();
    int cur = 0;

    for (int q = 0; q < QS; ++q) {
        const float* cfq = cbf + (size_t)q * KS * DIM;

        float bv0 = -INFINITY, bv1 = -INFINITY, bv2 = -INFINITY, bv3 = -INFINITY;
        int   bi0 = 0, bi1 = 0, bi2 = 0, bi3 = 0;

        for (int p = 0; p < 8; ++p) {
            const int gp = (q << 3) | p;            // global pair 0..63
            if (gp + 1 < 64) {                      // prefetch next pair
                STAGE(2 * gp + 2, cur ^ 1, 0);
                STAGE(2 * gp + 3, cur ^ 1, 1);
            }

            _Float16* base = smem + cur * (2 * CHUNK_H);
            CHUNKBODY(base,           (p * 2 + 0) * 4);
            CHUNKBODY(base + CHUNK_H, (p * 2 + 1) * 4);

            // barrier (with implicit vmcnt/lgkm drain): staged pair gp+1
            // resident; all waves done reading buffer cur.
            __syncthreads();
            cur ^= 1;
        }

        // reduce over the 4 quad-lanes holding the same token (disjoint codewords):
        // 2 shuffle steps. Tie-break: lowest index, matching jnp.argmin.
#define REDUCE(BV, BI) {                                                          \
        _Pragma("unroll")                                                         \
        for (int mask = 16; mask <= 32; mask <<= 1) {                             \
            float ov = __shfl_xor(BV, mask, 64);                                  \
            int   oi = __shfl_xor(BI, mask, 64);                                  \
            if (ov > BV || (ov == BV && oi < BI)) { BV = ov; BI = oi; }           \
        }                                                                         \
    }
        REDUCE(bv0, bi0); REDUCE(bv1, bi1); REDUCE(bv2, bi2); REDUCE(bv3, bi3);

        // index writes: quad s writes set s's token (64 lanes = 64 tokens)
        {
            const int myTok = tokenBase + quad * 16 + m;
            const int mybi  = (quad == 0) ? bi0 : (quad == 1) ? bi1
                            : (quad == 2) ? bi2 : bi3;
            out[(size_t)N_TOK * DIM + (size_t)myTok * QS + q] = (float)mybi;
        }

        // residual update per set: reconstruct r, subtract fp32 codeword, re-split
        float ls = 0.f;
#define RESID(BI, TH0, TH1, TL0, TL1, TS0, TS1) {                                 \
        const float* cp = cfq + (size_t)(BI) * DIM + quad * 8;                    \
        f32x4 c0 = *(const f32x4*)(cp);                                           \
        f32x4 c1 = *(const f32x4*)(cp + 4);                                       \
        f32x4 c2 = *(const f32x4*)(cp + 32);                                      \
        f32x4 c3 = *(const f32x4*)(cp + 36);                                      \
        _Pragma("unroll")                                                         \
        for (int j = 0; j < 4; ++j) {                                             \
            float v0 = fmaf(RISCALE, (float)TL0[j],   (float)TH0[j])   - c0[j];   \
            float v1 = fmaf(RISCALE, (float)TL0[j+4], (float)TH0[j+4]) - c1[j];   \
            float v2 = fmaf(RISCALE, (float)TL1[j],   (float)TH1[j])   - c2[j];   \
            float v3 = fmaf(RISCALE, (float)TL1[j+4], (float)TH1[j+4]) - c3[j];   \
            ls = fmaf(v0, v0, ls); ls = fmaf(v1, v1, ls);                         \
            ls = fmaf(v2, v2, ls); ls = fmaf(v3, v3, ls);                         \
            SPLIT3(v0, TH0[j],   TL0[j],   TS0[j]);                               \
            SPLIT3(v1, TH0[j+4], TL0[j+4], TS0[j+4]);                             \
            SPLIT3(v2, TH1[j],   TL1[j],   TS1[j]);                               \
            SPLIT3(v3, TH1[j+4], TL1[j+4], TS1[j+4]);                             \
        }                                                                         \
    }
        RESID(bi0, th00, th01, tl00, tl01, ts00, ts01);
        RESID(bi1, th10, th11, tl10, tl11, ts10, ts11);
        RESID(bi2, th20, th21, tl20, tl21, ts20, ts21);
        RESID(bi3, th30, th31, tl30, tl31, ts30, ts31);

#pragma unroll
        for (int mask = 1; mask <= 32; mask <<= 1) ls += __shfl_xor(ls, mask, 64);
        if (lane == 0)
            atomicAdd(out + (size_t)N_TOK * DIM + (size_t)N_TOK * QS + q,
                      ls * (1.0f / ((float)N_TOK * (float)DIM)));
    }

    // xq = x - r_final (reconstruct final residual from limbs), per set
#define XQW(S, TH0, TH1, TL0, TL1) {                                              \
        const size_t ra = (size_t)(tokenBase + (S) * 16 + m) * DIM + quad * 8;    \
        f32x4 a0 = __builtin_nontemporal_load((const f32x4*)(x + ra));            \
        f32x4 a1 = __builtin_nontemporal_load((const f32x4*)(x + ra + 4));        \
        f32x4 a2 = __builtin_nontemporal_load((const f32x4*)(x + ra + 32));       \
        f32x4 a3 = __builtin_nontemporal_load((const f32x4*)(x + ra + 36));       \
        _Pragma("unroll")                                                         \
        for (int j = 0; j < 4; ++j) {                                             \
            a0[j] -= fmaf(RISCALE, (float)TL0[j],   (float)TH0[j]);               \
            a1[j] -= fmaf(RISCALE, (float)TL0[j+4], (float)TH0[j+4]);             \
            a2[j] -= fmaf(RISCALE, (float)TL1[j],   (float)TH1[j]);               \
            a3[j] -= fmaf(RISCALE, (float)TL1[j+4], (float)TH1[j+4]);             \
        }                                                                         \
        __builtin_nontemporal_store(a0, (f32x4*)(out + ra));                      \
        __builtin_nontemporal_store(a1, (f32x4*)(out + ra + 4));                  \
        __builtin_nontemporal_store(a2, (f32x4*)(out + ra + 32));                 \
        __builtin_nontemporal_store(a3, (f32x4*)(out + ra + 36));                 \
    }
    XQW(0, th00, th01, tl00, tl01);
    XQW(1, th10, th11, tl10, tl11);
    XQW(2, th20, th21, tl20, tl21);
    XQW(3, th30, th31, tl30, tl31);

#undef MFMA24
#undef ARGMIN
#undef CHUNKBODY
#undef STAGE
#undef LOADTOK
#undef REDUCE
#undef RESID
#undef XQW
}

extern "C" void kernel_launch(void* const* d_in, const int* in_sizes, int n_in,
                              void* d_out, int out_size, void* d_ws, size_t ws_size,
                              hipStream_t stream) {
    const float* x   = (const float*)d_in[0];   // (N, D)
    const float* cb  = (const float*)d_in[1];   // (Q, K, D)
    float*       out = (float*)d_out;           // [xq | indices | losses]
    char*        ws  = (char*)d_ws;

    _Float16* G = (_Float16*)ws;   // 128 chunks x 16640 B = 2,129,920 B

    hipMemsetAsync(out + (size_t)N_TOK * DIM + (size_t)N_TOK * QS, 0,
                   QS * sizeof(float), stream);

    conv_kernel<<<512, 256, 0, stream>>>(cb, G);
    dc2_kernel<<<(QS * KS + 255) / 256, 256, 0, stream>>>(cb, (float*)ws);
    rvq_mfma_kernel<<<N_TOK / 256, 256, 4 * CHUNK_H * sizeof(_Float16), stream>>>(
        x, cb, G, out);
}